// Round 6
// baseline (534.209 us; speedup 1.0000x reference)
//
#include <hip/hip_runtime.h>

#define HID 64
#define IN_CH 128

typedef __attribute__((ext_vector_type(8))) short bf16x8;
typedef __attribute__((ext_vector_type(4))) float f32x4;

// ---------- bf16 helpers (RNE) ----------
__device__ __forceinline__ float bf2f(unsigned short u) {
    return __uint_as_float((unsigned)u << 16);
}
__device__ __forceinline__ unsigned short f2bf(float f) {
    unsigned u = __float_as_uint(f);
    unsigned r = u + 0x7FFFu + ((u >> 16) & 1u);
    return (unsigned short)(r >> 16);
}

// ============ CSR build ============

__global__ __launch_bounds__(256) void hist_kernel(const int* __restrict__ dst,
                                                   int* __restrict__ cnt, int E) {
    int e = blockIdx.x * 256 + threadIdx.x;
    if (e < E) atomicAdd(&cnt[dst[e]], 1);
}

__global__ __launch_bounds__(256) void block_sum_kernel(const int* __restrict__ cnt,
                                                        int* __restrict__ bsum, int N) {
    int i = blockIdx.x * 256 + threadIdx.x;
    int v = (i < N) ? cnt[i] : 0;
#pragma unroll
    for (int m = 1; m < 64; m <<= 1) v += __shfl_xor(v, m);
    __shared__ int wsm[4];
    if ((threadIdx.x & 63) == 0) wsm[threadIdx.x >> 6] = v;
    __syncthreads();
    if (threadIdx.x == 0) bsum[blockIdx.x] = wsm[0] + wsm[1] + wsm[2] + wsm[3];
}

__global__ __launch_bounds__(512) void scan_bsum_kernel(int* __restrict__ bsum,
                                                        int* __restrict__ off,
                                                        int NB, int N, int E) {
    __shared__ int sm[512];
    __shared__ int carry;
    const int t = threadIdx.x;
    if (t == 0) carry = 0;
    __syncthreads();
    for (int base = 0; base < NB; base += 512) {
        const int idx = base + t;
        const int v = (idx < NB) ? bsum[idx] : 0;
        sm[t] = v;
        __syncthreads();
        for (int d = 1; d < 512; d <<= 1) {
            int x = sm[t];
            int y = (t >= d) ? sm[t - d] : 0;
            __syncthreads();
            sm[t] = x + y;
            __syncthreads();
        }
        if (idx < NB) bsum[idx] = carry + sm[t] - v;
        __syncthreads();
        if (t == 0) carry += sm[511];
        __syncthreads();
    }
    if (t == 0) off[N] = E;
}

// exclusive scan within block + add block offset; also emits dinv = rsqrt(deg+1)
__global__ __launch_bounds__(256) void block_scan_kernel(const int* __restrict__ cnt,
                                                         const int* __restrict__ bsum,
                                                         int* __restrict__ off,
                                                         float* __restrict__ dinv, int N) {
    __shared__ int sm[256];
    const int i = blockIdx.x * 256 + threadIdx.x;
    const int t = threadIdx.x;
    const int v = (i < N) ? cnt[i] : 0;
    sm[t] = v;
    __syncthreads();
    for (int d = 1; d < 256; d <<= 1) {
        int x = sm[t];
        int y = (t >= d) ? sm[t - d] : 0;
        __syncthreads();
        sm[t] = x + y;
        __syncthreads();
    }
    if (i < N) {
        off[i] = bsum[blockIdx.x] + sm[t] - v;  // exclusive
        dinv[i] = rsqrtf((float)v + 1.0f);      // +1 self-loop
    }
}

// packed edge record: .x = src node, .y = float bits of dinv[s]*dinv[d]
// slot-claim by decrementing cnt (order within a segment is irrelevant)
__global__ __launch_bounds__(256) void scatter_kernel(
    const int* __restrict__ src, const int* __restrict__ dst,
    const int* __restrict__ off, int* __restrict__ cnt,
    const float* __restrict__ dinv, int2* __restrict__ epk, int E) {
    int e = blockIdx.x * 256 + threadIdx.x;
    if (e < E) {
        const int d = dst[e];
        const int s = src[e];
        const int p = off[d] + atomicSub(&cnt[d], 1) - 1;
        int2 r;
        r.x = s;
        r.y = __float_as_int(dinv[s] * dinv[d]);
        epk[p] = r;
    }
}

// ============ weight prep: transpose to bf16 [n][k] ============
__global__ __launch_bounds__(256) void prep_weights_kernel(
    const float* __restrict__ pw, const float* __restrict__ w0,
    const float* __restrict__ w1, const float* __restrict__ w2,
    unsigned short* __restrict__ pwT, unsigned short* __restrict__ wT) {
    const int id = blockIdx.x;
    if (id == 0) {
        for (int i = threadIdx.x; i < IN_CH * HID; i += 256) {
            const int k = i >> 6, n = i & 63;
            pwT[n * IN_CH + k] = f2bf(pw[i]);
        }
    } else {
        const float* w = (id == 1) ? w0 : (id == 2) ? w1 : w2;
        unsigned short* o = wT + (id - 1) * HID * HID;
        for (int i = threadIdx.x; i < HID * HID; i += 256) {
            const int k = i >> 6, n = i & 63;
            o[n * HID + k] = f2bf(w[i]);
        }
    }
}

// ============ input projection: res = x@pw + pb (fp32), hbf = bf16(res) ====
__global__ __launch_bounds__(256) void proj_mfma_kernel(
    const float* __restrict__ A, const unsigned short* __restrict__ wT,
    const float* __restrict__ bias, float* __restrict__ res,
    unsigned short* __restrict__ hbf, int N) {
    constexpr int K = IN_CH;
    const int wave = threadIdx.x >> 6;
    const int lane = threadIdx.x & 63;
    const int quad = lane >> 4;
    const int m = lane & 15;
    const int rowbase = blockIdx.x * 64 + wave * 16;
    const int row = rowbase + m;

    f32x4 acc[4];
#pragma unroll
    for (int nt = 0; nt < 4; nt++) acc[nt] = (f32x4){0.f, 0.f, 0.f, 0.f};

#pragma unroll
    for (int ks = 0; ks < K; ks += 32) {
        union { bf16x8 v; unsigned short u[8]; } af;
        if (row < N) {
            const float4 a0 = *(const float4*)&A[(size_t)row * K + ks + quad * 8];
            const float4 a1 = *(const float4*)&A[(size_t)row * K + ks + quad * 8 + 4];
            af.u[0] = f2bf(a0.x); af.u[1] = f2bf(a0.y);
            af.u[2] = f2bf(a0.z); af.u[3] = f2bf(a0.w);
            af.u[4] = f2bf(a1.x); af.u[5] = f2bf(a1.y);
            af.u[6] = f2bf(a1.z); af.u[7] = f2bf(a1.w);
        } else {
#pragma unroll
            for (int j = 0; j < 8; j++) af.u[j] = 0;
        }
#pragma unroll
        for (int nt = 0; nt < 4; nt++) {
            const int n = nt * 16 + m;
            const bf16x8 bfrag = *(const bf16x8*)&wT[n * K + ks + quad * 8];
            acc[nt] = __builtin_amdgcn_mfma_f32_16x16x32_bf16(af.v, bfrag, acc[nt], 0, 0, 0);
        }
    }

#pragma unroll
    for (int nt = 0; nt < 4; nt++) {
#pragma unroll
        for (int r = 0; r < 4; r++) {
            const int orow = rowbase + quad * 4 + r;
            if (orow < N) {
                const int col = nt * 16 + m;
                const size_t o = (size_t)orow * HID + col;
                const float v = acc[nt][r] + bias[col];
                res[o] = v;
                hbf[o] = f2bf(v);
            }
        }
    }
}

// ============ fused layer: gather-agg -> LDS -> MFMA(W) -> LN -> epilogue ===
// block = 128 threads (2 waves), 32 rows. Wave w aggregates rows [w*16,w*16+16)
// into LDS, then MFMAs its 16 rows x 64 cols with K=64.
// NOTE: hbf_in and hbf_out MUST be different buffers (cross-block gather race).
// LAST=false: res += relu(LN(aggW+b)); hbf_out = bf16(res)
// LAST=true : out = LN(aggW+b)
template <bool LAST>
__global__ __launch_bounds__(128) void layer_kernel(
    const int* __restrict__ off, const int2* __restrict__ epk,
    const float* __restrict__ dinv, const unsigned short* __restrict__ hbf_in,
    const unsigned short* __restrict__ wT, const float* __restrict__ bias,
    const float* __restrict__ g, const float* __restrict__ beta,
    float* __restrict__ res, unsigned short* __restrict__ hbf_out,
    float* __restrict__ out, int N) {
    constexpr int RS = HID + 4;  // 68-float LDS row stride: 2-way banks only
    __shared__ float agg[32 * RS];

    const int wave = threadIdx.x >> 6;  // 0..1
    const int lane = threadIdx.x & 63;
    const int quad = lane >> 4;
    const int m = lane & 15;
    const int blockrow = blockIdx.x * 32;

    // ---- phase 1: gather-aggregate (lane = channel) ----
    for (int rr = 0; rr < 16; ++rr) {
        const int row = blockrow + wave * 16 + rr;
        float acc0 = 0.f, acc1 = 0.f, acc2 = 0.f, acc3 = 0.f;
        if (row < N) {
            const float di = dinv[row];
            acc0 = bf2f(hbf_in[(size_t)row * HID + lane]) * di * di;  // self-loop
            int p = off[row];
            const int p1 = off[row + 1];
            for (; p + 4 <= p1; p += 4) {
                const int2 e0 = epk[p];
                const int2 e1 = epk[p + 1];
                const int2 e2 = epk[p + 2];
                const int2 e3 = epk[p + 3];
                const float h0 = bf2f(hbf_in[(size_t)e0.x * HID + lane]);
                const float h1 = bf2f(hbf_in[(size_t)e1.x * HID + lane]);
                const float h2 = bf2f(hbf_in[(size_t)e2.x * HID + lane]);
                const float h3 = bf2f(hbf_in[(size_t)e3.x * HID + lane]);
                acc0 += h0 * __int_as_float(e0.y);
                acc1 += h1 * __int_as_float(e1.y);
                acc2 += h2 * __int_as_float(e2.y);
                acc3 += h3 * __int_as_float(e3.y);
            }
            for (; p < p1; ++p) {
                const int2 e = epk[p];
                acc0 += bf2f(hbf_in[(size_t)e.x * HID + lane]) * __int_as_float(e.y);
            }
        }
        agg[(wave * 16 + rr) * RS + lane] = (acc0 + acc1) + (acc2 + acc3);
    }
    __syncthreads();

    // ---- phase 2: MFMA (A = agg rows from LDS, B = wT) ----
    const int wbase = wave * 16;
    f32x4 acc[4];
#pragma unroll
    for (int nt = 0; nt < 4; nt++) acc[nt] = (f32x4){0.f, 0.f, 0.f, 0.f};

#pragma unroll
    for (int ks = 0; ks < HID; ks += 32) {
        union { bf16x8 v; unsigned short u[8]; } af;
        const float* ap = &agg[(wbase + m) * RS + ks + quad * 8];
#pragma unroll
        for (int j = 0; j < 8; j++) af.u[j] = f2bf(ap[j]);
#pragma unroll
        for (int nt = 0; nt < 4; nt++) {
            const bf16x8 bfrag = *(const bf16x8*)&wT[(nt * 16 + m) * HID + ks + quad * 8];
            acc[nt] = __builtin_amdgcn_mfma_f32_16x16x32_bf16(af.v, bfrag, acc[nt], 0, 0, 0);
        }
    }

    // ---- epilogue: +bias, LN per row (reduce over 16-lane quad), relu+res ----
    float bv[4], gv[4], betav[4];
#pragma unroll
    for (int nt = 0; nt < 4; nt++) {
        const int col = nt * 16 + m;
        bv[nt] = bias[col];
        gv[nt] = g[col];
        betav[nt] = beta[col];
    }
#pragma unroll
    for (int r = 0; r < 4; r++) {
        const int orow = blockrow + wbase + quad * 4 + r;
        if (orow >= N) continue;
        float v[4];
        float s = 0.f;
#pragma unroll
        for (int nt = 0; nt < 4; nt++) {
            v[nt] = acc[nt][r] + bv[nt];
            s += v[nt];
        }
#pragma unroll
        for (int mask = 1; mask < 16; mask <<= 1) s += __shfl_xor(s, mask);
        const float mean = s * (1.0f / 64.0f);
        float q = 0.f;
#pragma unroll
        for (int nt = 0; nt < 4; nt++) {
            const float d = v[nt] - mean;
            q += d * d;
        }
#pragma unroll
        for (int mask = 1; mask < 16; mask <<= 1) q += __shfl_xor(q, mask);
        const float rstd = rsqrtf(q * (1.0f / 64.0f) + 1e-5f);
#pragma unroll
        for (int nt = 0; nt < 4; nt++) {
            const float y = (v[nt] - mean) * rstd * gv[nt] + betav[nt];
            const size_t o = (size_t)orow * HID + nt * 16 + m;
            if (LAST) {
                out[o] = y;
            } else {
                const float w2 = fmaxf(y, 0.f) + res[o];
                res[o] = w2;
                hbf_out[o] = f2bf(w2);
            }
        }
    }
}

extern "C" void kernel_launch(void* const* d_in, const int* in_sizes, int n_in,
                              void* d_out, int out_size, void* d_ws, size_t ws_size,
                              hipStream_t stream) {
    const float* x      = (const float*)d_in[0];
    const int*   ei     = (const int*)d_in[1];
    const float* proj_w = (const float*)d_in[2];
    const float* proj_b = (const float*)d_in[3];
    const float* w[3]  = {(const float*)d_in[4], (const float*)d_in[8],  (const float*)d_in[12]};
    const float* b[3]  = {(const float*)d_in[5], (const float*)d_in[9],  (const float*)d_in[13]};
    const float* g[3]  = {(const float*)d_in[6], (const float*)d_in[10], (const float*)d_in[14]};
    const float* be[3] = {(const float*)d_in[7], (const float*)d_in[11], (const float*)d_in[15]};

    const int N = in_sizes[0] / IN_CH;
    const int E = in_sizes[1] / 2;
    const int* src = ei;
    const int* dst = ei + E;
    const int NB = (N + 255) / 256;

    char* wsb = (char*)d_ws;
    size_t o2 = 0;
    auto alloc = [&](size_t bytes) {
        void* p = wsb + o2;
        o2 = (o2 + bytes + 255) & ~(size_t)255;
        return p;
    };
    int*   cnt   = (int*)alloc((size_t)N * 4);
    int*   off   = (int*)alloc((size_t)(N + 1) * 4);
    int*   bsum  = (int*)alloc((size_t)NB * 4);
    float* dinv  = (float*)alloc((size_t)N * 4);
    int2*  epk   = (int2*)alloc((size_t)E * 8);
    float* res   = (float*)alloc((size_t)N * HID * 4);                    // residual fp32
    unsigned short* hbfA = (unsigned short*)alloc((size_t)N * HID * 2);   // h bf16 ping
    unsigned short* hbfB = (unsigned short*)alloc((size_t)N * HID * 2);   // h bf16 pong
    unsigned short* pwT = (unsigned short*)alloc((size_t)HID * IN_CH * 2);
    unsigned short* wT  = (unsigned short*)alloc((size_t)3 * HID * HID * 2);

    // ---- CSR build ----
    hipMemsetAsync(cnt, 0, (size_t)N * 4, stream);
    hist_kernel<<<(E + 255) / 256, 256, 0, stream>>>(dst, cnt, E);
    block_sum_kernel<<<NB, 256, 0, stream>>>(cnt, bsum, N);
    scan_bsum_kernel<<<1, 512, 0, stream>>>(bsum, off, NB, N, E);
    block_scan_kernel<<<NB, 256, 0, stream>>>(cnt, bsum, off, dinv, N);
    scatter_kernel<<<(E + 255) / 256, 256, 0, stream>>>(src, dst, off, cnt, dinv,
                                                        epk, E);
    prep_weights_kernel<<<4, 256, 0, stream>>>(proj_w, w[0], w[1], w[2], pwT, wT);

    // ---- input projection ----
    proj_mfma_kernel<<<(N + 63) / 64, 256, 0, stream>>>(x, pwT, proj_b, res, hbfA, N);

    // ---- 3 fused GCN layers (ping-pong hbf buffers) ----
    layer_kernel<false><<<(N + 31) / 32, 128, 0, stream>>>(
        off, epk, dinv, hbfA, wT + 0 * HID * HID, b[0], g[0], be[0],
        res, hbfB, nullptr, N);
    layer_kernel<false><<<(N + 31) / 32, 128, 0, stream>>>(
        off, epk, dinv, hbfB, wT + 1 * HID * HID, b[1], g[1], be[1],
        res, hbfA, nullptr, N);
    layer_kernel<true><<<(N + 31) / 32, 128, 0, stream>>>(
        off, epk, dinv, hbfA, wT + 2 * HID * HID, b[2], g[2], be[2],
        nullptr, nullptr, (float*)d_out, N);
}

// Round 7
// 451.283 us; speedup vs baseline: 1.1838x; 1.1838x over previous
//
#include <hip/hip_runtime.h>

#define HID 64
#define IN_CH 128

typedef __attribute__((ext_vector_type(8))) short bf16x8;
typedef __attribute__((ext_vector_type(4))) float f32x4;

// ---------- bf16 helpers (RNE) ----------
__device__ __forceinline__ float bf2f(unsigned short u) {
    return __uint_as_float((unsigned)u << 16);
}
__device__ __forceinline__ unsigned short f2bf(float f) {
    unsigned u = __float_as_uint(f);
    unsigned r = u + 0x7FFFu + ((u >> 16) & 1u);
    return (unsigned short)(r >> 16);
}

// ============ CSR build ============

__global__ __launch_bounds__(256) void hist_kernel(const int* __restrict__ dst,
                                                   int* __restrict__ cnt, int E) {
    int e = blockIdx.x * 256 + threadIdx.x;
    if (e < E) atomicAdd(&cnt[dst[e]], 1);
}

__global__ __launch_bounds__(256) void block_sum_kernel(const int* __restrict__ cnt,
                                                        int* __restrict__ bsum, int N) {
    int i = blockIdx.x * 256 + threadIdx.x;
    int v = (i < N) ? cnt[i] : 0;
#pragma unroll
    for (int m = 1; m < 64; m <<= 1) v += __shfl_xor(v, m);
    __shared__ int wsm[4];
    if ((threadIdx.x & 63) == 0) wsm[threadIdx.x >> 6] = v;
    __syncthreads();
    if (threadIdx.x == 0) bsum[blockIdx.x] = wsm[0] + wsm[1] + wsm[2] + wsm[3];
}

// block 0: chunked exclusive scan of bsum (512 threads).
// blocks 1..4: weight transpose to bf16 [n][k] (fused to save a dispatch).
__global__ __launch_bounds__(512) void scan_prep_kernel(
    int* __restrict__ bsum, int* __restrict__ off, int NB, int N, int E,
    const float* __restrict__ pw, const float* __restrict__ w0,
    const float* __restrict__ w1, const float* __restrict__ w2,
    unsigned short* __restrict__ pwT, unsigned short* __restrict__ wT) {
    const int id = blockIdx.x;
    if (id == 0) {
        __shared__ int sm[512];
        __shared__ int carry;
        const int t = threadIdx.x;
        if (t == 0) carry = 0;
        __syncthreads();
        for (int base = 0; base < NB; base += 512) {
            const int idx = base + t;
            const int v = (idx < NB) ? bsum[idx] : 0;
            sm[t] = v;
            __syncthreads();
            for (int d = 1; d < 512; d <<= 1) {
                int x = sm[t];
                int y = (t >= d) ? sm[t - d] : 0;
                __syncthreads();
                sm[t] = x + y;
                __syncthreads();
            }
            if (idx < NB) bsum[idx] = carry + sm[t] - v;
            __syncthreads();
            if (t == 0) carry += sm[511];
            __syncthreads();
        }
        if (t == 0) off[N] = E;
    } else if (id == 1) {
        for (int i = threadIdx.x; i < IN_CH * HID; i += 512) {
            const int k = i >> 6, n = i & 63;
            pwT[n * IN_CH + k] = f2bf(pw[i]);
        }
    } else {
        const float* w = (id == 2) ? w0 : (id == 3) ? w1 : w2;
        unsigned short* o = wT + (id - 2) * HID * HID;
        for (int i = threadIdx.x; i < HID * HID; i += 512) {
            const int k = i >> 6, n = i & 63;
            o[n * HID + k] = f2bf(w[i]);
        }
    }
}

// exclusive scan within block + block offset; emits dinv = rsqrt(deg+1)
__global__ __launch_bounds__(256) void block_scan_kernel(const int* __restrict__ cnt,
                                                         const int* __restrict__ bsum,
                                                         int* __restrict__ off,
                                                         float* __restrict__ dinv, int N) {
    __shared__ int sm[256];
    const int i = blockIdx.x * 256 + threadIdx.x;
    const int t = threadIdx.x;
    const int v = (i < N) ? cnt[i] : 0;
    sm[t] = v;
    __syncthreads();
    for (int d = 1; d < 256; d <<= 1) {
        int x = sm[t];
        int y = (t >= d) ? sm[t - d] : 0;
        __syncthreads();
        sm[t] = x + y;
        __syncthreads();
    }
    if (i < N) {
        off[i] = bsum[blockIdx.x] + sm[t] - v;  // exclusive
        dinv[i] = rsqrtf((float)v + 1.0f);      // +1 self-loop
    }
}

// dst-sorted src index; slot-claim by decrementing cnt (order irrelevant)
__global__ __launch_bounds__(256) void scatter_kernel(
    const int* __restrict__ src, const int* __restrict__ dst,
    const int* __restrict__ off, int* __restrict__ cnt,
    int* __restrict__ ssrc, int E) {
    int e = blockIdx.x * 256 + threadIdx.x;
    if (e < E) {
        const int d = dst[e];
        const int p = off[d] + atomicSub(&cnt[d], 1) - 1;
        ssrc[p] = src[e];
    }
}

// ============ input projection: res = bf16(x@pw + pb) ============
__global__ __launch_bounds__(256) void proj_mfma_kernel(
    const float* __restrict__ A, const unsigned short* __restrict__ wT,
    const float* __restrict__ bias, unsigned short* __restrict__ res, int N) {
    constexpr int K = IN_CH;
    const int wave = threadIdx.x >> 6;
    const int lane = threadIdx.x & 63;
    const int quad = lane >> 4;
    const int m = lane & 15;
    const int rowbase = blockIdx.x * 64 + wave * 16;
    const int row = rowbase + m;

    f32x4 acc[4];
#pragma unroll
    for (int nt = 0; nt < 4; nt++) acc[nt] = (f32x4){0.f, 0.f, 0.f, 0.f};

#pragma unroll
    for (int ks = 0; ks < K; ks += 32) {
        union { bf16x8 v; unsigned short u[8]; } af;
        if (row < N) {
            const float4 a0 = *(const float4*)&A[(size_t)row * K + ks + quad * 8];
            const float4 a1 = *(const float4*)&A[(size_t)row * K + ks + quad * 8 + 4];
            af.u[0] = f2bf(a0.x); af.u[1] = f2bf(a0.y);
            af.u[2] = f2bf(a0.z); af.u[3] = f2bf(a0.w);
            af.u[4] = f2bf(a1.x); af.u[5] = f2bf(a1.y);
            af.u[6] = f2bf(a1.z); af.u[7] = f2bf(a1.w);
        } else {
#pragma unroll
            for (int j = 0; j < 8; j++) af.u[j] = 0;
        }
#pragma unroll
        for (int nt = 0; nt < 4; nt++) {
            const bf16x8 bfrag = *(const bf16x8*)&wT[(nt * 16 + m) * K + ks + quad * 8];
            acc[nt] = __builtin_amdgcn_mfma_f32_16x16x32_bf16(af.v, bfrag, acc[nt], 0, 0, 0);
        }
    }

#pragma unroll
    for (int nt = 0; nt < 4; nt++) {
#pragma unroll
        for (int r = 0; r < 4; r++) {
            const int orow = rowbase + quad * 4 + r;
            if (orow < N) {
                const int col = nt * 16 + m;
                res[(size_t)orow * HID + col] = f2bf(acc[nt][r] + bias[col]);
            }
        }
    }
}

// ============ layer GEMM: hw = bf16( res(bf16)[N,64] @ W[64,64] ) ============
__global__ __launch_bounds__(256) void gemm_mfma_kernel(
    const unsigned short* __restrict__ res, const unsigned short* __restrict__ wT,
    unsigned short* __restrict__ hw, int N) {
    constexpr int K = HID;
    const int wave = threadIdx.x >> 6;
    const int lane = threadIdx.x & 63;
    const int quad = lane >> 4;
    const int m = lane & 15;
    const int rowbase = blockIdx.x * 64 + wave * 16;
    const int row = rowbase + m;

    f32x4 acc[4];
#pragma unroll
    for (int nt = 0; nt < 4; nt++) acc[nt] = (f32x4){0.f, 0.f, 0.f, 0.f};

#pragma unroll
    for (int ks = 0; ks < K; ks += 32) {
        bf16x8 af;
        if (row < N) {
            af = *(const bf16x8*)&res[(size_t)row * K + ks + quad * 8];
        } else {
            af = (bf16x8){0, 0, 0, 0, 0, 0, 0, 0};
        }
#pragma unroll
        for (int nt = 0; nt < 4; nt++) {
            const bf16x8 bfrag = *(const bf16x8*)&wT[(nt * 16 + m) * K + ks + quad * 8];
            acc[nt] = __builtin_amdgcn_mfma_f32_16x16x32_bf16(af, bfrag, acc[nt], 0, 0, 0);
        }
    }

#pragma unroll
    for (int nt = 0; nt < 4; nt++) {
#pragma unroll
        for (int r = 0; r < 4; r++) {
            const int orow = rowbase + quad * 4 + r;
            if (orow < N) {
                hw[(size_t)orow * HID + nt * 16 + m] = f2bf(acc[nt][r]);
            }
        }
    }
}

// ============ fused aggregate + LayerNorm (+relu+residual) ============
// one wave per row, lane = channel. norm computed from dinv (L2-hot).
// LAST=false: res(bf16) += relu(LN(acc)) in place ; LAST=true: out(fp32) = LN(acc)
template <bool LAST>
__global__ __launch_bounds__(256) void agg_ln_kernel(
    const int* __restrict__ off, const int* __restrict__ ssrc,
    const float* __restrict__ dinv, const unsigned short* __restrict__ hw,
    const float* __restrict__ bias, const float* __restrict__ g,
    const float* __restrict__ beta, unsigned short* __restrict__ res,
    float* __restrict__ out, int N) {
    const int row = blockIdx.x * 4 + (threadIdx.x >> 6);
    if (row >= N) return;
    const int c = threadIdx.x & 63;
    const size_t o = (size_t)row * HID + c;

    const float di = dinv[row];
    float acc0 = bias[c] + bf2f(hw[o]) * di * di;  // self-loop
    float acc1 = 0.0f, acc2 = 0.0f, acc3 = 0.0f;

    int p = off[row];
    const int p1 = off[row + 1];
    for (; p + 4 <= p1; p += 4) {
        const int s0 = ssrc[p];
        const int s1 = ssrc[p + 1];
        const int s2 = ssrc[p + 2];
        const int s3 = ssrc[p + 3];
        const float n0 = dinv[s0] * di;
        const float n1 = dinv[s1] * di;
        const float n2 = dinv[s2] * di;
        const float n3 = dinv[s3] * di;
        acc0 += bf2f(hw[(size_t)s0 * HID + c]) * n0;
        acc1 += bf2f(hw[(size_t)s1 * HID + c]) * n1;
        acc2 += bf2f(hw[(size_t)s2 * HID + c]) * n2;
        acc3 += bf2f(hw[(size_t)s3 * HID + c]) * n3;
    }
    for (; p < p1; ++p) {
        const int s = ssrc[p];
        acc0 += bf2f(hw[(size_t)s * HID + c]) * (dinv[s] * di);
    }
    float acc = (acc0 + acc1) + (acc2 + acc3);

    // LayerNorm over 64 channels (one wave)
    float su = acc;
#pragma unroll
    for (int m = 1; m < 64; m <<= 1) su += __shfl_xor(su, m);
    const float mean = su * (1.0f / 64.0f);
    const float d = acc - mean;
    float q = d * d;
#pragma unroll
    for (int m = 1; m < 64; m <<= 1) q += __shfl_xor(q, m);
    const float var = q * (1.0f / 64.0f);
    const float y = d * rsqrtf(var + 1e-5f) * g[c] + beta[c];

    if (LAST) {
        out[o] = y;
    } else {
        res[o] = f2bf(fmaxf(y, 0.0f) + bf2f(res[o]));  // in-place: own row only
    }
}

extern "C" void kernel_launch(void* const* d_in, const int* in_sizes, int n_in,
                              void* d_out, int out_size, void* d_ws, size_t ws_size,
                              hipStream_t stream) {
    const float* x      = (const float*)d_in[0];
    const int*   ei     = (const int*)d_in[1];
    const float* proj_w = (const float*)d_in[2];
    const float* proj_b = (const float*)d_in[3];
    const float* w[3]  = {(const float*)d_in[4], (const float*)d_in[8],  (const float*)d_in[12]};
    const float* b[3]  = {(const float*)d_in[5], (const float*)d_in[9],  (const float*)d_in[13]};
    const float* g[3]  = {(const float*)d_in[6], (const float*)d_in[10], (const float*)d_in[14]};
    const float* be[3] = {(const float*)d_in[7], (const float*)d_in[11], (const float*)d_in[15]};

    const int N = in_sizes[0] / IN_CH;
    const int E = in_sizes[1] / 2;
    const int* src = ei;
    const int* dst = ei + E;
    const int NB = (N + 255) / 256;

    char* wsb = (char*)d_ws;
    size_t o2 = 0;
    auto alloc = [&](size_t bytes) {
        void* p = wsb + o2;
        o2 = (o2 + bytes + 255) & ~(size_t)255;
        return p;
    };
    int*   cnt   = (int*)alloc((size_t)N * 4);
    int*   off   = (int*)alloc((size_t)(N + 1) * 4);
    int*   bsum  = (int*)alloc((size_t)NB * 4);
    float* dinv  = (float*)alloc((size_t)N * 4);
    int*   ssrc  = (int*)alloc((size_t)E * 4);
    unsigned short* res = (unsigned short*)alloc((size_t)N * HID * 2);  // residual bf16
    unsigned short* hw  = (unsigned short*)alloc((size_t)N * HID * 2);  // h@W bf16
    unsigned short* pwT = (unsigned short*)alloc((size_t)HID * IN_CH * 2);
    unsigned short* wT  = (unsigned short*)alloc((size_t)3 * HID * HID * 2);

    // ---- CSR build (+ weight prep fused into scan dispatch) ----
    hipMemsetAsync(cnt, 0, (size_t)N * 4, stream);
    hist_kernel<<<(E + 255) / 256, 256, 0, stream>>>(dst, cnt, E);
    block_sum_kernel<<<NB, 256, 0, stream>>>(cnt, bsum, N);
    scan_prep_kernel<<<5, 512, 0, stream>>>(bsum, off, NB, N, E,
                                            proj_w, w[0], w[1], w[2], pwT, wT);
    block_scan_kernel<<<NB, 256, 0, stream>>>(cnt, bsum, off, dinv, N);
    scatter_kernel<<<(E + 255) / 256, 256, 0, stream>>>(src, dst, off, cnt, ssrc, E);

    // ---- input projection ----
    proj_mfma_kernel<<<(N + 63) / 64, 256, 0, stream>>>(x, pwT, proj_b, res, N);

    // ---- 3 GCN layers (split: gemm then agg; hw read-only during agg) ----
    for (int l = 0; l < 3; l++) {
        gemm_mfma_kernel<<<(N + 63) / 64, 256, 0, stream>>>(
            res, wT + (size_t)l * HID * HID, hw, N);
        if (l < 2) {
            agg_ln_kernel<false><<<(N + 3) / 4, 256, 0, stream>>>(
                off, ssrc, dinv, hw, b[l], g[l], be[l], res, nullptr, N);
        } else {
            agg_ln_kernel<true><<<(N + 3) / 4, 256, 0, stream>>>(
                off, ssrc, dinv, hw, b[l], g[l], be[l], nullptr, (float*)d_out, N);
        }
    }
}

// Round 8
// 435.483 us; speedup vs baseline: 1.2267x; 1.0363x over previous
//
#include <hip/hip_runtime.h>

#define HID 64
#define IN_CH 128

#define BSHIFT 9          // 512 nodes per bucket
#define NBUK_MAX 256      // supports N up to 131072
#define EPB 2048          // edges per partition block

typedef __attribute__((ext_vector_type(8))) short bf16x8;
typedef __attribute__((ext_vector_type(4))) float f32x4;

// ---------- bf16 helpers (RNE) ----------
__device__ __forceinline__ float bf2f(unsigned short u) {
    return __uint_as_float((unsigned)u << 16);
}
__device__ __forceinline__ unsigned short f2bf(float f) {
    unsigned u = __float_as_uint(f);
    unsigned r = u + 0x7FFFu + ((u >> 16) & 1u);
    return (unsigned short)(r >> 16);
}

// ============ CSR build ============

__global__ __launch_bounds__(256) void hist_kernel(const int* __restrict__ dst,
                                                   int* __restrict__ cnt, int E) {
    int e = blockIdx.x * 256 + threadIdx.x;
    if (e < E) atomicAdd(&cnt[dst[e]], 1);
}

__global__ __launch_bounds__(256) void block_sum_kernel(const int* __restrict__ cnt,
                                                        int* __restrict__ bsum, int N) {
    int i = blockIdx.x * 256 + threadIdx.x;
    int v = (i < N) ? cnt[i] : 0;
#pragma unroll
    for (int m = 1; m < 64; m <<= 1) v += __shfl_xor(v, m);
    __shared__ int wsm[4];
    if ((threadIdx.x & 63) == 0) wsm[threadIdx.x >> 6] = v;
    __syncthreads();
    if (threadIdx.x == 0) bsum[blockIdx.x] = wsm[0] + wsm[1] + wsm[2] + wsm[3];
}

// block 0: chunked exclusive scan of bsum (512 threads).
// blocks 1..4: weight transpose to bf16 [n][k] (fused to save a dispatch).
__global__ __launch_bounds__(512) void scan_prep_kernel(
    int* __restrict__ bsum, int* __restrict__ off, int NB, int N, int E,
    const float* __restrict__ pw, const float* __restrict__ w0,
    const float* __restrict__ w1, const float* __restrict__ w2,
    unsigned short* __restrict__ pwT, unsigned short* __restrict__ wT) {
    const int id = blockIdx.x;
    if (id == 0) {
        __shared__ int sm[512];
        __shared__ int carry;
        const int t = threadIdx.x;
        if (t == 0) carry = 0;
        __syncthreads();
        for (int base = 0; base < NB; base += 512) {
            const int idx = base + t;
            const int v = (idx < NB) ? bsum[idx] : 0;
            sm[t] = v;
            __syncthreads();
            for (int d = 1; d < 512; d <<= 1) {
                int x = sm[t];
                int y = (t >= d) ? sm[t - d] : 0;
                __syncthreads();
                sm[t] = x + y;
                __syncthreads();
            }
            if (idx < NB) bsum[idx] = carry + sm[t] - v;
            __syncthreads();
            if (t == 0) carry += sm[511];
            __syncthreads();
        }
        if (t == 0) off[N] = E;
    } else if (id == 1) {
        for (int i = threadIdx.x; i < IN_CH * HID; i += 512) {
            const int k = i >> 6, n = i & 63;
            pwT[n * IN_CH + k] = f2bf(pw[i]);
        }
    } else {
        const float* w = (id == 2) ? w0 : (id == 3) ? w1 : w2;
        unsigned short* o = wT + (id - 2) * HID * HID;
        for (int i = threadIdx.x; i < HID * HID; i += 512) {
            const int k = i >> 6, n = i & 63;
            o[n * HID + k] = f2bf(w[i]);
        }
    }
}

// exclusive scan within block + block offset; emits dinv = rsqrt(deg+1)
__global__ __launch_bounds__(256) void block_scan_kernel(const int* __restrict__ cnt,
                                                         const int* __restrict__ bsum,
                                                         int* __restrict__ off,
                                                         float* __restrict__ dinv, int N) {
    __shared__ int sm[256];
    const int i = blockIdx.x * 256 + threadIdx.x;
    const int t = threadIdx.x;
    const int v = (i < N) ? cnt[i] : 0;
    sm[t] = v;
    __syncthreads();
    for (int d = 1; d < 256; d <<= 1) {
        int x = sm[t];
        int y = (t >= d) ? sm[t - d] : 0;
        __syncthreads();
        sm[t] = x + y;
        __syncthreads();
    }
    if (i < N) {
        off[i] = bsum[blockIdx.x] + sm[t] - v;  // exclusive
        dinv[i] = rsqrtf((float)v + 1.0f);      // +1 self-loop
    }
}

// gcursor[b] = start of bucket b's edge region (= off[first node of bucket])
__global__ __launch_bounds__(256) void gcursor_init_kernel(
    const int* __restrict__ off, int* __restrict__ gcursor, int nbuk) {
    const int b = threadIdx.x;
    if (b < nbuk) gcursor[b] = off[b << BSHIFT];
}

// ---- partition pass: LDS counting-sort edges by bucket, write (src,dst)
//      pairs bucket-contiguously into binned[] (regions match final CSR) ----
__global__ __launch_bounds__(256) void partition_kernel(
    const int* __restrict__ src, const int* __restrict__ dst,
    int* __restrict__ gcursor, int2* __restrict__ binned, int E) {
    __shared__ int lh[NBUK_MAX];     // per-bucket count (atomic rank)
    __shared__ int loff[NBUK_MAX];   // exclusive scan of counts
    __shared__ int gbase[NBUK_MAX];  // global base per bucket
    __shared__ int2 stage[EPB];

    const int t = threadIdx.x;
    const int base = blockIdx.x * EPB;
    const int count = min(EPB, E - base);

    for (int i = t; i < NBUK_MAX; i += 256) lh[i] = 0;
    __syncthreads();

    constexpr int EPT = EPB / 256;  // edges per thread
    int myS[EPT], myD[EPT], myR[EPT];
#pragma unroll
    for (int j = 0; j < EPT; ++j) {
        const int e = base + j * 256 + t;
        if (e < E) {
            myS[j] = src[e];
            myD[j] = dst[e];
            myR[j] = atomicAdd(&lh[myD[j] >> BSHIFT], 1);
        }
    }
    __syncthreads();

    // exclusive scan of lh -> loff (256 == NBUK_MAX threads)
    const int v = lh[t];
    loff[t] = v;
    __syncthreads();
    for (int d = 1; d < 256; d <<= 1) {
        int x = loff[t];
        int y = (t >= d) ? loff[t - d] : 0;
        __syncthreads();
        loff[t] = x + y;
        __syncthreads();
    }
    const int excl = loff[t] - v;
    __syncthreads();
    loff[t] = excl;
    if (v > 0) gbase[t] = atomicAdd(&gcursor[t], v);
    __syncthreads();

    // stage into LDS sorted by bucket
#pragma unroll
    for (int j = 0; j < EPT; ++j) {
        const int e = base + j * 256 + t;
        if (e < E) {
            const int b = myD[j] >> BSHIFT;
            stage[loff[b] + myR[j]] = make_int2(myS[j], myD[j]);
        }
    }
    __syncthreads();

    // write out: consecutive LDS slots within a bucket -> consecutive global
    for (int i = t; i < count; i += 256) {
        const int2 ed = stage[i];
        const int b = ed.y >> BSHIFT;
        binned[gbase[b] + (i - loff[b])] = ed;
    }
}

// ---- final scatter: writes random only within a ~20KB bucket window ----
__global__ __launch_bounds__(256) void scatter2_kernel(
    const int2* __restrict__ binned, const int* __restrict__ off,
    int* __restrict__ cnt, int* __restrict__ ssrc, int E) {
    int e = blockIdx.x * 256 + threadIdx.x;
    if (e < E) {
        const int2 ed = binned[e];
        const int p = off[ed.y] + atomicSub(&cnt[ed.y], 1) - 1;
        ssrc[p] = ed.x;
    }
}

// ============ input projection: res = bf16(x@pw + pb) ============
__global__ __launch_bounds__(256) void proj_mfma_kernel(
    const float* __restrict__ A, const unsigned short* __restrict__ wT,
    const float* __restrict__ bias, unsigned short* __restrict__ res, int N) {
    constexpr int K = IN_CH;
    const int wave = threadIdx.x >> 6;
    const int lane = threadIdx.x & 63;
    const int quad = lane >> 4;
    const int m = lane & 15;
    const int rowbase = blockIdx.x * 64 + wave * 16;
    const int row = rowbase + m;

    f32x4 acc[4];
#pragma unroll
    for (int nt = 0; nt < 4; nt++) acc[nt] = (f32x4){0.f, 0.f, 0.f, 0.f};

#pragma unroll
    for (int ks = 0; ks < K; ks += 32) {
        union { bf16x8 v; unsigned short u[8]; } af;
        if (row < N) {
            const float4 a0 = *(const float4*)&A[(size_t)row * K + ks + quad * 8];
            const float4 a1 = *(const float4*)&A[(size_t)row * K + ks + quad * 8 + 4];
            af.u[0] = f2bf(a0.x); af.u[1] = f2bf(a0.y);
            af.u[2] = f2bf(a0.z); af.u[3] = f2bf(a0.w);
            af.u[4] = f2bf(a1.x); af.u[5] = f2bf(a1.y);
            af.u[6] = f2bf(a1.z); af.u[7] = f2bf(a1.w);
        } else {
#pragma unroll
            for (int j = 0; j < 8; j++) af.u[j] = 0;
        }
#pragma unroll
        for (int nt = 0; nt < 4; nt++) {
            const bf16x8 bfrag = *(const bf16x8*)&wT[(nt * 16 + m) * K + ks + quad * 8];
            acc[nt] = __builtin_amdgcn_mfma_f32_16x16x32_bf16(af.v, bfrag, acc[nt], 0, 0, 0);
        }
    }

#pragma unroll
    for (int nt = 0; nt < 4; nt++) {
#pragma unroll
        for (int r = 0; r < 4; r++) {
            const int orow = rowbase + quad * 4 + r;
            if (orow < N) {
                const int col = nt * 16 + m;
                res[(size_t)orow * HID + col] = f2bf(acc[nt][r] + bias[col]);
            }
        }
    }
}

// ============ layer GEMM: hw = bf16( res(bf16)[N,64] @ W[64,64] ) ============
__global__ __launch_bounds__(256) void gemm_mfma_kernel(
    const unsigned short* __restrict__ res, const unsigned short* __restrict__ wT,
    unsigned short* __restrict__ hw, int N) {
    constexpr int K = HID;
    const int wave = threadIdx.x >> 6;
    const int lane = threadIdx.x & 63;
    const int quad = lane >> 4;
    const int m = lane & 15;
    const int rowbase = blockIdx.x * 64 + wave * 16;
    const int row = rowbase + m;

    f32x4 acc[4];
#pragma unroll
    for (int nt = 0; nt < 4; nt++) acc[nt] = (f32x4){0.f, 0.f, 0.f, 0.f};

#pragma unroll
    for (int ks = 0; ks < K; ks += 32) {
        bf16x8 af;
        if (row < N) {
            af = *(const bf16x8*)&res[(size_t)row * K + ks + quad * 8];
        } else {
            af = (bf16x8){0, 0, 0, 0, 0, 0, 0, 0};
        }
#pragma unroll
        for (int nt = 0; nt < 4; nt++) {
            const bf16x8 bfrag = *(const bf16x8*)&wT[(nt * 16 + m) * K + ks + quad * 8];
            acc[nt] = __builtin_amdgcn_mfma_f32_16x16x32_bf16(af, bfrag, acc[nt], 0, 0, 0);
        }
    }

#pragma unroll
    for (int nt = 0; nt < 4; nt++) {
#pragma unroll
        for (int r = 0; r < 4; r++) {
            const int orow = rowbase + quad * 4 + r;
            if (orow < N) {
                hw[(size_t)orow * HID + nt * 16 + m] = f2bf(acc[nt][r]);
            }
        }
    }
}

// ============ fused aggregate + LayerNorm (+relu+residual) ============
// one wave per row, lane = channel. norm computed from dinv (L2-hot).
// LAST=false: res(bf16) += relu(LN(acc)) in place ; LAST=true: out(fp32) = LN(acc)
template <bool LAST>
__global__ __launch_bounds__(256) void agg_ln_kernel(
    const int* __restrict__ off, const int* __restrict__ ssrc,
    const float* __restrict__ dinv, const unsigned short* __restrict__ hw,
    const float* __restrict__ bias, const float* __restrict__ g,
    const float* __restrict__ beta, unsigned short* __restrict__ res,
    float* __restrict__ out, int N) {
    const int row = blockIdx.x * 4 + (threadIdx.x >> 6);
    if (row >= N) return;
    const int c = threadIdx.x & 63;
    const size_t o = (size_t)row * HID + c;

    const float di = dinv[row];
    float acc0 = bias[c] + bf2f(hw[o]) * di * di;  // self-loop
    float acc1 = 0.0f, acc2 = 0.0f, acc3 = 0.0f;

    int p = off[row];
    const int p1 = off[row + 1];
    for (; p + 4 <= p1; p += 4) {
        const int s0 = ssrc[p];
        const int s1 = ssrc[p + 1];
        const int s2 = ssrc[p + 2];
        const int s3 = ssrc[p + 3];
        const float n0 = dinv[s0] * di;
        const float n1 = dinv[s1] * di;
        const float n2 = dinv[s2] * di;
        const float n3 = dinv[s3] * di;
        acc0 += bf2f(hw[(size_t)s0 * HID + c]) * n0;
        acc1 += bf2f(hw[(size_t)s1 * HID + c]) * n1;
        acc2 += bf2f(hw[(size_t)s2 * HID + c]) * n2;
        acc3 += bf2f(hw[(size_t)s3 * HID + c]) * n3;
    }
    for (; p < p1; ++p) {
        const int s = ssrc[p];
        acc0 += bf2f(hw[(size_t)s * HID + c]) * (dinv[s] * di);
    }
    float acc = (acc0 + acc1) + (acc2 + acc3);

    // LayerNorm over 64 channels (one wave)
    float su = acc;
#pragma unroll
    for (int m = 1; m < 64; m <<= 1) su += __shfl_xor(su, m);
    const float mean = su * (1.0f / 64.0f);
    const float d = acc - mean;
    float q = d * d;
#pragma unroll
    for (int m = 1; m < 64; m <<= 1) q += __shfl_xor(q, m);
    const float var = q * (1.0f / 64.0f);
    const float y = d * rsqrtf(var + 1e-5f) * g[c] + beta[c];

    if (LAST) {
        out[o] = y;
    } else {
        res[o] = f2bf(fmaxf(y, 0.0f) + bf2f(res[o]));  // in-place: own row only
    }
}

extern "C" void kernel_launch(void* const* d_in, const int* in_sizes, int n_in,
                              void* d_out, int out_size, void* d_ws, size_t ws_size,
                              hipStream_t stream) {
    const float* x      = (const float*)d_in[0];
    const int*   ei     = (const int*)d_in[1];
    const float* proj_w = (const float*)d_in[2];
    const float* proj_b = (const float*)d_in[3];
    const float* w[3]  = {(const float*)d_in[4], (const float*)d_in[8],  (const float*)d_in[12]};
    const float* b[3]  = {(const float*)d_in[5], (const float*)d_in[9],  (const float*)d_in[13]};
    const float* g[3]  = {(const float*)d_in[6], (const float*)d_in[10], (const float*)d_in[14]};
    const float* be[3] = {(const float*)d_in[7], (const float*)d_in[11], (const float*)d_in[15]};

    const int N = in_sizes[0] / IN_CH;
    const int E = in_sizes[1] / 2;
    const int* src = ei;
    const int* dst = ei + E;
    const int NB = (N + 255) / 256;
    const int nbuk = (N + (1 << BSHIFT) - 1) >> BSHIFT;

    char* wsb = (char*)d_ws;
    size_t o2 = 0;
    auto alloc = [&](size_t bytes) {
        void* p = wsb + o2;
        o2 = (o2 + bytes + 255) & ~(size_t)255;
        return p;
    };
    int*   cnt     = (int*)alloc((size_t)N * 4);
    int*   off     = (int*)alloc((size_t)(N + 1) * 4);
    int*   bsum    = (int*)alloc((size_t)NB * 4);
    float* dinv    = (float*)alloc((size_t)N * 4);
    int*   gcursor = (int*)alloc((size_t)NBUK_MAX * 4);
    int2*  binned  = (int2*)alloc((size_t)E * 8);
    int*   ssrc    = (int*)alloc((size_t)E * 4);
    unsigned short* res = (unsigned short*)alloc((size_t)N * HID * 2);  // residual bf16
    unsigned short* hw  = (unsigned short*)alloc((size_t)N * HID * 2);  // h@W bf16
    unsigned short* pwT = (unsigned short*)alloc((size_t)HID * IN_CH * 2);
    unsigned short* wT  = (unsigned short*)alloc((size_t)3 * HID * HID * 2);

    // ---- CSR build (+ weight prep fused into scan dispatch) ----
    hipMemsetAsync(cnt, 0, (size_t)N * 4, stream);
    hist_kernel<<<(E + 255) / 256, 256, 0, stream>>>(dst, cnt, E);
    block_sum_kernel<<<NB, 256, 0, stream>>>(cnt, bsum, N);
    scan_prep_kernel<<<5, 512, 0, stream>>>(bsum, off, NB, N, E,
                                            proj_w, w[0], w[1], w[2], pwT, wT);
    block_scan_kernel<<<NB, 256, 0, stream>>>(cnt, bsum, off, dinv, N);
    gcursor_init_kernel<<<1, 256, 0, stream>>>(off, gcursor, nbuk);
    partition_kernel<<<(E + EPB - 1) / EPB, 256, 0, stream>>>(src, dst, gcursor,
                                                              binned, E);
    scatter2_kernel<<<(E + 255) / 256, 256, 0, stream>>>(binned, off, cnt, ssrc, E);

    // ---- input projection ----
    proj_mfma_kernel<<<(N + 63) / 64, 256, 0, stream>>>(x, pwT, proj_b, res, N);

    // ---- 3 GCN layers (split: gemm then agg; hw read-only during agg) ----
    for (int l = 0; l < 3; l++) {
        gemm_mfma_kernel<<<(N + 63) / 64, 256, 0, stream>>>(
            res, wT + (size_t)l * HID * HID, hw, N);
        if (l < 2) {
            agg_ln_kernel<false><<<(N + 3) / 4, 256, 0, stream>>>(
                off, ssrc, dinv, hw, b[l], g[l], be[l], res, nullptr, N);
        } else {
            agg_ln_kernel<true><<<(N + 3) / 4, 256, 0, stream>>>(
                off, ssrc, dinv, hw, b[l], g[l], be[l], nullptr, (float*)d_out, N);
        }
    }
}

// Round 9
// 375.268 us; speedup vs baseline: 1.4235x; 1.1605x over previous
//
#include <hip/hip_runtime.h>

#define HID 64
#define IN_CH 128

#define BSHIFT 9          // 512 nodes per bucket
#define NBUK_MAX 256      // supports N up to 131072 (src packed in 17 bits)
#define EPB 2048          // edges per partition block
#define EPH 4096          // edges per bucket_hist block

typedef __attribute__((ext_vector_type(8))) short bf16x8;
typedef __attribute__((ext_vector_type(4))) float f32x4;

// ---------- bf16 helpers (RNE) ----------
__device__ __forceinline__ float bf2f(unsigned short u) {
    return __uint_as_float((unsigned)u << 16);
}
__device__ __forceinline__ unsigned short f2bf(float f) {
    unsigned u = __float_as_uint(f);
    unsigned r = u + 0x7FFFu + ((u >> 16) & 1u);
    return (unsigned short)(r >> 16);
}

// ============ CSR build (bucket-native) ============

// per-block LDS histogram of bucket ids, merged to global
__global__ __launch_bounds__(256) void bucket_hist_kernel(const int* __restrict__ dst,
                                                          int* __restrict__ gbucket,
                                                          int E) {
    __shared__ int lh[NBUK_MAX];
    const int t = threadIdx.x;
    for (int i = t; i < NBUK_MAX; i += 256) lh[i] = 0;
    __syncthreads();
    const int base = blockIdx.x * EPH;
#pragma unroll
    for (int j = 0; j < EPH / 256; ++j) {
        const int e = base + j * 256 + t;
        if (e < E) atomicAdd(&lh[dst[e] >> BSHIFT], 1);
    }
    __syncthreads();
    for (int i = t; i < NBUK_MAX; i += 256)
        if (lh[i]) atomicAdd(&gbucket[i], lh[i]);
}

// block 0: exclusive scan of gbucket -> boff (pristine) + gcursor (working);
//          also off[N]=E, boff[NBUK_MAX]=E.
// blocks 1..4: weight transpose to bf16 [n][k].
__global__ __launch_bounds__(512) void scan_prep_kernel(
    const int* __restrict__ gbucket, int* __restrict__ boff,
    int* __restrict__ gcursor, int* __restrict__ off, int N, int E,
    const float* __restrict__ pw, const float* __restrict__ w0,
    const float* __restrict__ w1, const float* __restrict__ w2,
    unsigned short* __restrict__ pwT, unsigned short* __restrict__ wT) {
    const int id = blockIdx.x;
    const int t = threadIdx.x;
    if (id == 0) {
        __shared__ int sm[512];
        const int v = (t < NBUK_MAX) ? gbucket[t] : 0;
        sm[t] = v;
        __syncthreads();
        for (int d = 1; d < 512; d <<= 1) {
            int x = sm[t];
            int y = (t >= d) ? sm[t - d] : 0;
            __syncthreads();
            sm[t] = x + y;
            __syncthreads();
        }
        if (t < NBUK_MAX) {
            const int excl = sm[t] - v;
            boff[t] = excl;
            gcursor[t] = excl;
        }
        if (t == 0) {
            boff[NBUK_MAX] = E;
            off[N] = E;
        }
    } else if (id == 1) {
        for (int i = t; i < IN_CH * HID; i += 512) {
            const int k = i >> 6, n = i & 63;
            pwT[n * IN_CH + k] = f2bf(pw[i]);
        }
    } else {
        const float* w = (id == 2) ? w0 : (id == 3) ? w1 : w2;
        unsigned short* o = wT + (id - 2) * HID * HID;
        for (int i = t; i < HID * HID; i += 512) {
            const int k = i >> 6, n = i & 63;
            o[n * HID + k] = f2bf(w[i]);
        }
    }
}

// ---- partition: LDS counting-sort by bucket, write packed src|(dlocal<<17)
//      bucket-contiguously into binned[] (regions match final CSR) ----
__global__ __launch_bounds__(256) void partition_kernel(
    const int* __restrict__ src, const int* __restrict__ dst,
    int* __restrict__ gcursor, int* __restrict__ binned, int E) {
    __shared__ int lh[NBUK_MAX];     // per-bucket count (atomic rank)
    __shared__ int loff[NBUK_MAX];   // exclusive scan of counts
    __shared__ int gbase[NBUK_MAX];  // global base per bucket
    __shared__ int2 stage[EPB];

    const int t = threadIdx.x;
    const int base = blockIdx.x * EPB;
    const int count = min(EPB, E - base);

    for (int i = t; i < NBUK_MAX; i += 256) lh[i] = 0;
    __syncthreads();

    constexpr int EPT = EPB / 256;
    int myS[EPT], myD[EPT], myR[EPT];
#pragma unroll
    for (int j = 0; j < EPT; ++j) {
        const int e = base + j * 256 + t;
        if (e < E) {
            myS[j] = src[e];
            myD[j] = dst[e];
            myR[j] = atomicAdd(&lh[myD[j] >> BSHIFT], 1);
        }
    }
    __syncthreads();

    const int v = lh[t];
    loff[t] = v;
    __syncthreads();
    for (int d = 1; d < 256; d <<= 1) {
        int x = loff[t];
        int y = (t >= d) ? loff[t - d] : 0;
        __syncthreads();
        loff[t] = x + y;
        __syncthreads();
    }
    const int excl = loff[t] - v;
    __syncthreads();
    loff[t] = excl;
    if (v > 0) gbase[t] = atomicAdd(&gcursor[t], v);
    __syncthreads();

#pragma unroll
    for (int j = 0; j < EPT; ++j) {
        const int e = base + j * 256 + t;
        if (e < E) {
            const int b = myD[j] >> BSHIFT;
            stage[loff[b] + myR[j]] = make_int2(myS[j], myD[j]);
        }
    }
    __syncthreads();

    for (int i = t; i < count; i += 256) {
        const int2 ed = stage[i];
        const int b = ed.y >> BSHIFT;
        const int pk = ed.x | ((ed.y & ((1 << BSHIFT) - 1)) << 17);
        binned[gbase[b] + (i - loff[b])] = pk;
    }
}

// ---- one block per bucket: node hist -> scan -> off/dinv/ssrc ----
__global__ __launch_bounds__(512) void bucket_csr_kernel(
    const int* __restrict__ binned, const int* __restrict__ boff,
    int* __restrict__ off, float* __restrict__ dinv,
    int* __restrict__ ssrc, int N) {
    __shared__ int lh[512];
    __shared__ int lo[512];
    const int b = blockIdx.x;
    const int t = threadIdx.x;
    const int e0 = boff[b], e1 = boff[b + 1];

    lh[t] = 0;
    __syncthreads();
    for (int e = e0 + t; e < e1; e += 512)
        atomicAdd(&lh[binned[e] >> 17], 1);
    __syncthreads();

    const int v = lh[t];
    lo[t] = v;
    __syncthreads();
    for (int d = 1; d < 512; d <<= 1) {
        int x = lo[t];
        int y = (t >= d) ? lo[t - d] : 0;
        __syncthreads();
        lo[t] = x + y;
        __syncthreads();
    }
    const int excl = lo[t] - v;
    const int node = (b << BSHIFT) + t;
    if (node < N) {
        off[node] = e0 + excl;
        dinv[node] = rsqrtf((float)v + 1.0f);  // +1 self-loop
    }
    __syncthreads();
    lh[t] = excl;  // reuse as cursor
    __syncthreads();
    for (int e = e0 + t; e < e1; e += 512) {
        const int pk = binned[e];
        const int p = atomicAdd(&lh[pk >> 17], 1);
        ssrc[e0 + p] = pk & 0x1FFFF;  // random only within ~20KB window
    }
}

// ============ input projection: res = bf16(x@pw + pb) ============
__global__ __launch_bounds__(256) void proj_mfma_kernel(
    const float* __restrict__ A, const unsigned short* __restrict__ wT,
    const float* __restrict__ bias, unsigned short* __restrict__ res, int N) {
    constexpr int K = IN_CH;
    const int wave = threadIdx.x >> 6;
    const int lane = threadIdx.x & 63;
    const int quad = lane >> 4;
    const int m = lane & 15;
    const int rowbase = blockIdx.x * 64 + wave * 16;
    const int row = rowbase + m;

    f32x4 acc[4];
#pragma unroll
    for (int nt = 0; nt < 4; nt++) acc[nt] = (f32x4){0.f, 0.f, 0.f, 0.f};

#pragma unroll
    for (int ks = 0; ks < K; ks += 32) {
        union { bf16x8 v; unsigned short u[8]; } af;
        if (row < N) {
            const float4 a0 = *(const float4*)&A[(size_t)row * K + ks + quad * 8];
            const float4 a1 = *(const float4*)&A[(size_t)row * K + ks + quad * 8 + 4];
            af.u[0] = f2bf(a0.x); af.u[1] = f2bf(a0.y);
            af.u[2] = f2bf(a0.z); af.u[3] = f2bf(a0.w);
            af.u[4] = f2bf(a1.x); af.u[5] = f2bf(a1.y);
            af.u[6] = f2bf(a1.z); af.u[7] = f2bf(a1.w);
        } else {
#pragma unroll
            for (int j = 0; j < 8; j++) af.u[j] = 0;
        }
#pragma unroll
        for (int nt = 0; nt < 4; nt++) {
            const bf16x8 bfrag = *(const bf16x8*)&wT[(nt * 16 + m) * K + ks + quad * 8];
            acc[nt] = __builtin_amdgcn_mfma_f32_16x16x32_bf16(af.v, bfrag, acc[nt], 0, 0, 0);
        }
    }

#pragma unroll
    for (int nt = 0; nt < 4; nt++) {
#pragma unroll
        for (int r = 0; r < 4; r++) {
            const int orow = rowbase + quad * 4 + r;
            if (orow < N) {
                const int col = nt * 16 + m;
                res[(size_t)orow * HID + col] = f2bf(acc[nt][r] + bias[col]);
            }
        }
    }
}

// ============ layer GEMM: hw = bf16( (res@W) * dinv[row] ) — prescaled ======
__global__ __launch_bounds__(256) void gemm_mfma_kernel(
    const unsigned short* __restrict__ res, const unsigned short* __restrict__ wT,
    const float* __restrict__ dinv, unsigned short* __restrict__ hw, int N) {
    constexpr int K = HID;
    const int wave = threadIdx.x >> 6;
    const int lane = threadIdx.x & 63;
    const int quad = lane >> 4;
    const int m = lane & 15;
    const int rowbase = blockIdx.x * 64 + wave * 16;
    const int row = rowbase + m;

    f32x4 acc[4];
#pragma unroll
    for (int nt = 0; nt < 4; nt++) acc[nt] = (f32x4){0.f, 0.f, 0.f, 0.f};

#pragma unroll
    for (int ks = 0; ks < K; ks += 32) {
        bf16x8 af;
        if (row < N) {
            af = *(const bf16x8*)&res[(size_t)row * K + ks + quad * 8];
        } else {
            af = (bf16x8){0, 0, 0, 0, 0, 0, 0, 0};
        }
#pragma unroll
        for (int nt = 0; nt < 4; nt++) {
            const bf16x8 bfrag = *(const bf16x8*)&wT[(nt * 16 + m) * K + ks + quad * 8];
            acc[nt] = __builtin_amdgcn_mfma_f32_16x16x32_bf16(af, bfrag, acc[nt], 0, 0, 0);
        }
    }

#pragma unroll
    for (int r = 0; r < 4; r++) {
        const int orow = rowbase + quad * 4 + r;
        if (orow < N) {
            const float di = dinv[orow];
#pragma unroll
            for (int nt = 0; nt < 4; nt++) {
                hw[(size_t)orow * HID + nt * 16 + m] = f2bf(acc[nt][r] * di);
            }
        }
    }
}

// ============ fused aggregate + LayerNorm (+relu+residual) ============
// hw is prescaled by dinv. out_row = di*(hw[row] + sum_edges hw[s]) + bias.
// Masked 4-wide edge loop: all gathers independent (max MLP).
// LAST=false: res(bf16) += relu(LN(...)) in place ; LAST=true: out(fp32) = LN(...)
template <bool LAST>
__global__ __launch_bounds__(256) void agg_ln_kernel(
    const int* __restrict__ off, const int* __restrict__ ssrc,
    const float* __restrict__ dinv, const unsigned short* __restrict__ hw,
    const float* __restrict__ bias, const float* __restrict__ g,
    const float* __restrict__ beta, unsigned short* __restrict__ res,
    float* __restrict__ out, int N) {
    const int row = blockIdx.x * 4 + (threadIdx.x >> 6);
    if (row >= N) return;
    const int c = threadIdx.x & 63;
    const size_t o = (size_t)row * HID + c;

    const float di = dinv[row];
    float acc0 = bf2f(hw[o]);  // self-loop (prescaled)
    float acc1 = 0.0f, acc2 = 0.0f, acc3 = 0.0f;

    const int p0 = off[row];
    const int p1 = off[row + 1];
    for (int p = p0; p < p1; p += 4) {
        const int q1 = p + 1, q2 = p + 2, q3 = p + 3;
        const int s0 = ssrc[p];
        const int s1 = ssrc[q1 < p1 ? q1 : p];
        const int s2 = ssrc[q2 < p1 ? q2 : p];
        const int s3 = ssrc[q3 < p1 ? q3 : p];
        const float m1 = (q1 < p1) ? 1.0f : 0.0f;
        const float m2 = (q2 < p1) ? 1.0f : 0.0f;
        const float m3 = (q3 < p1) ? 1.0f : 0.0f;
        acc0 += bf2f(hw[(size_t)s0 * HID + c]);
        acc1 += bf2f(hw[(size_t)s1 * HID + c]) * m1;
        acc2 += bf2f(hw[(size_t)s2 * HID + c]) * m2;
        acc3 += bf2f(hw[(size_t)s3 * HID + c]) * m3;
    }
    float acc = ((acc0 + acc1) + (acc2 + acc3)) * di + bias[c];

    // LayerNorm over 64 channels (one wave)
    float su = acc;
#pragma unroll
    for (int m = 1; m < 64; m <<= 1) su += __shfl_xor(su, m);
    const float mean = su * (1.0f / 64.0f);
    const float d = acc - mean;
    float q = d * d;
#pragma unroll
    for (int m = 1; m < 64; m <<= 1) q += __shfl_xor(q, m);
    const float var = q * (1.0f / 64.0f);
    const float y = d * rsqrtf(var + 1e-5f) * g[c] + beta[c];

    if (LAST) {
        out[o] = y;
    } else {
        res[o] = f2bf(fmaxf(y, 0.0f) + bf2f(res[o]));  // in-place: own row only
    }
}

extern "C" void kernel_launch(void* const* d_in, const int* in_sizes, int n_in,
                              void* d_out, int out_size, void* d_ws, size_t ws_size,
                              hipStream_t stream) {
    const float* x      = (const float*)d_in[0];
    const int*   ei     = (const int*)d_in[1];
    const float* proj_w = (const float*)d_in[2];
    const float* proj_b = (const float*)d_in[3];
    const float* w[3]  = {(const float*)d_in[4], (const float*)d_in[8],  (const float*)d_in[12]};
    const float* b[3]  = {(const float*)d_in[5], (const float*)d_in[9],  (const float*)d_in[13]};
    const float* g[3]  = {(const float*)d_in[6], (const float*)d_in[10], (const float*)d_in[14]};
    const float* be[3] = {(const float*)d_in[7], (const float*)d_in[11], (const float*)d_in[15]};

    const int N = in_sizes[0] / IN_CH;
    const int E = in_sizes[1] / 2;
    const int* src = ei;
    const int* dst = ei + E;
    const int nbuk = (N + (1 << BSHIFT) - 1) >> BSHIFT;

    char* wsb = (char*)d_ws;
    size_t o2 = 0;
    auto alloc = [&](size_t bytes) {
        void* p = wsb + o2;
        o2 = (o2 + bytes + 255) & ~(size_t)255;
        return p;
    };
    int*   gbucket = (int*)alloc((size_t)NBUK_MAX * 4);
    int*   boff    = (int*)alloc((size_t)(NBUK_MAX + 1) * 4);
    int*   gcursor = (int*)alloc((size_t)NBUK_MAX * 4);
    int*   off     = (int*)alloc((size_t)(N + 1) * 4);
    float* dinv    = (float*)alloc((size_t)N * 4);
    int*   binned  = (int*)alloc((size_t)E * 4);
    int*   ssrc    = (int*)alloc((size_t)E * 4);
    unsigned short* res = (unsigned short*)alloc((size_t)N * HID * 2);  // residual bf16
    unsigned short* hw  = (unsigned short*)alloc((size_t)N * HID * 2);  // (h@W)*dinv bf16
    unsigned short* pwT = (unsigned short*)alloc((size_t)HID * IN_CH * 2);
    unsigned short* wT  = (unsigned short*)alloc((size_t)3 * HID * HID * 2);

    // ---- bucket-native CSR build ----
    hipMemsetAsync(gbucket, 0, (size_t)NBUK_MAX * 4, stream);
    bucket_hist_kernel<<<(E + EPH - 1) / EPH, 256, 0, stream>>>(dst, gbucket, E);
    scan_prep_kernel<<<5, 512, 0, stream>>>(gbucket, boff, gcursor, off, N, E,
                                            proj_w, w[0], w[1], w[2], pwT, wT);
    partition_kernel<<<(E + EPB - 1) / EPB, 256, 0, stream>>>(src, dst, gcursor,
                                                              binned, E);
    bucket_csr_kernel<<<nbuk, 512, 0, stream>>>(binned, boff, off, dinv, ssrc, N);

    // ---- input projection ----
    proj_mfma_kernel<<<(N + 63) / 64, 256, 0, stream>>>(x, pwT, proj_b, res, N);

    // ---- 3 GCN layers (split: gemm then agg; hw read-only during agg) ----
    for (int l = 0; l < 3; l++) {
        gemm_mfma_kernel<<<(N + 63) / 64, 256, 0, stream>>>(
            res, wT + (size_t)l * HID * HID, dinv, hw, N);
        if (l < 2) {
            agg_ln_kernel<false><<<(N + 3) / 4, 256, 0, stream>>>(
                off, ssrc, dinv, hw, b[l], g[l], be[l], res, nullptr, N);
        } else {
            agg_ln_kernel<true><<<(N + 3) / 4, 256, 0, stream>>>(
                off, ssrc, dinv, hw, b[l], g[l], be[l], nullptr, (float*)d_out, N);
        }
    }
}